// Round 10
// baseline (88.945 us; speedup 1.0000x reference)
//
#include <hip/hip_runtime.h>

#define NN 4096
#define COL4 (NN / 4)      // 1024 float4 per row
#define BB 8
#define F_IN 40
#define HH 64
#define KW 5
#define LL (NN - KW + 1)   // 4092
#define RC 32              // row chunks for A passes (128 rows each)
#define CHUNK (NN / RC)    // 128

// workspace layout (floats)
#define OFF_P1 0                           // [RC][NN]     partial colsums
#define OFF_PE (OFF_P1 + RC * NN)          // [RC][8][NN]  partial e_s
#define OFF_U  (OFF_PE + RC * 8 * NN)      // [BB][NN]     u_b = x[b]·M0
#define OFF_M  (OFF_U + BB * NN)           // [9][F_IN]    adjoint map M
#define OFF_AB (OFF_M + 9 * F_IN)          // [9]          alpha, beta[8]
#define OFF_G9 (OFF_AB + 9)                // [9]          gamma pieces
#define OFF_RP (OFF_G9 + 9)                // [8][16]      rpart
#define OFF_ACC (OFF_RP + 128)             // [8]          dataAcc (atomic)
#define OFF_SCA (OFF_ACC + 8)              // [1]          sC accumulator (atomic)
#define OFF_TKT (OFF_SCA + 1)              // [1]          ticket counter (int)

__device__ __forceinline__ int special_row(int s) { return s < 4 ? s : (NN - 8 + s); }
__device__ __forceinline__ void f4add(float4& a, const float4& b) {
    a.x += b.x; a.y += b.y; a.z += b.z; a.w += b.w;
}
__device__ __forceinline__ void f4fma(float4& a, float w, const float4& b) {
    a.x += w * b.x; a.y += w * b.y; a.z += w * b.z; a.w += w * b.w;
}

// ============ k1: blocks 0..511 stream A (colsum+e_s partials, rpart);
//   512..520: per-v adjoint (M, AB, G9; v=0 block also resets accumulators);
//   521..584: u-blocks (u_b = x[b]·M0). grid 585, block 256.
__global__ __launch_bounds__(256) void k1(const float4* __restrict__ A4,
                                          const float* __restrict__ A,
                                          const float* __restrict__ x,
                                          float4* __restrict__ part1,
                                          float4* __restrict__ partE,
                                          float* __restrict__ rpart,
                                          const float* __restrict__ W1,
                                          const float* __restrict__ b1,
                                          const float* __restrict__ W2,
                                          const float* __restrict__ b2,
                                          const float* __restrict__ cw,
                                          const float* __restrict__ cb,
                                          const float* __restrict__ fw,
                                          const float* __restrict__ fb,
                                          float* __restrict__ Mout,
                                          float* __restrict__ ABout,
                                          float* __restrict__ G9out,
                                          float* __restrict__ u,
                                          float* __restrict__ dataAcc,
                                          float* __restrict__ sCacc,
                                          int* __restrict__ ticket) {
    __shared__ __align__(16) char sm[28928];
    const int tid = threadIdx.x;
    const int tx = tid & 63, ty = tid >> 6;
    if (blockIdx.x < 512) {
        float* wsh = (float*)sm;                                 // [8][128] 4 KB
        float4 (*red3)[3][64] = (float4 (*)[3][64])(sm + 4096);  // 12 KB
        const int bx = blockIdx.x & 15, by = blockIdx.x >> 4;
        const int m0 = by * CHUNK;
        for (int idx = tid; idx < 8 * CHUNK; idx += 256) {
            int s = idx >> 7, j = idx & 127;
            wsh[s * CHUNK + j] = A[(size_t)special_row(s) * NN + m0 + j];
        }
        __syncthreads();
        const int c4 = bx * 64 + tx;
        const float4* Ap = A4 + (size_t)(m0 + ty * 32) * COL4 + c4;
        float4 acc[9];
        #pragma unroll
        for (int v = 0; v < 9; ++v) acc[v] = make_float4(0.f, 0.f, 0.f, 0.f);
        #pragma unroll 4
        for (int j = 0; j < 32; ++j) {
            float4 a = Ap[(size_t)j * COL4];
            int jj = ty * 32 + j;
            f4add(acc[0], a);
            #pragma unroll
            for (int s = 0; s < 8; ++s) f4fma(acc[1 + s], wsh[s * CHUNK + jj], a);
        }
        #pragma unroll
        for (int g = 0; g < 3; ++g) {
            #pragma unroll
            for (int vv = 0; vv < 3; ++vv) red3[ty][vv][tx] = acc[g * 3 + vv];
            __syncthreads();
            if (ty == 0) {
                #pragma unroll
                for (int vv = 0; vv < 3; ++vv) {
                    int v = g * 3 + vv;
                    float4 t = red3[0][vv][tx];
                    f4add(t, red3[1][vv][tx]);
                    f4add(t, red3[2][vv][tx]);
                    f4add(t, red3[3][vv][tx]);
                    if (v == 0) part1[(size_t)by * COL4 + c4] = t;
                    else        partE[((size_t)by * 8 + (v - 1)) * COL4 + c4] = t;
                }
            }
            __syncthreads();
        }
        if ((by == 0 || by == 31) && ty == 0) {
            int sbase = (by == 0) ? 0 : 4;
            #pragma unroll
            for (int k = 0; k < 4; ++k) {
                float4 a = A4[(size_t)special_row(sbase + k) * COL4 + c4];
                float v = a.x + a.y + a.z + a.w;
                for (int off = 32; off > 0; off >>= 1) v += __shfl_down(v, off);
                if (tx == 0) rpart[(sbase + k) * 16 + bx] = v;
            }
        }
        return;
    }
    if (blockIdx.x < 521) {
        // ---- adjoint block for v (weights only, self-contained) ----
        const int v = blockIdx.x - 512;
        // v==0 block resets the k2 accumulators (kernel boundary orders k1<k2)
        if (v == 0) {
            if (tid >= 240 && tid < 248) dataAcc[tid - 240] = 0.f;
            if (tid == 248) sCacc[0] = 0.f;
            if (tid == 249) ticket[0] = 0;
        }
        float* W2s  = (float*)sm;            // [64*65]
        float* W1s  = W2s + 64 * 65;         // [40*65]
        float* Xp   = W1s + 40 * 65;         // [4][64]
        float* Xs   = Xp + 256;
        float* Ps   = Xs + 64;
        float* bw2s = Ps + 64;
        for (int idx = tid; idx < 64 * 64; idx += 256)
            W2s[(idx >> 6) * 65 + (idx & 63)] = W2[idx];
        for (int idx = tid; idx < 40 * 64; idx += 256)
            W1s[(idx >> 6) * 65 + (idx & 63)] = W1[idx];
        {
            float acc = 0.f;
            for (int oo = 0; oo < 16; ++oo) {
                int o = ty * 16 + oo;
                float f = fw[o];
                const float* cp = cw + ((size_t)o * HH + tx) * KW;
                float w0 = cp[0], w1 = cp[1], w2 = cp[2], w3 = cp[3], w4 = cp[4];
                float coef;
                switch (v) {
                    case 0: coef = w0 + w1 + w2 + w3 + w4; break;
                    case 1: coef = w1 + w2 + w3 + w4; break;
                    case 2: coef = w2 + w3 + w4; break;
                    case 3: coef = w3 + w4; break;
                    case 4: coef = w4; break;
                    case 5: coef = w0; break;
                    case 6: coef = w0 + w1; break;
                    case 7: coef = w0 + w1 + w2; break;
                    default: coef = w0 + w1 + w2 + w3; break;
                }
                acc += f * coef;
            }
            Xp[ty * 64 + tx] = acc;
        }
        __syncthreads();
        if (ty == 0) {
            float s = Xp[tx] + Xp[64 + tx] + Xp[128 + tx] + Xp[192 + tx];
            Xs[tx] = (v == 0 ? 1.f : -1.f) * s / (float)LL;
        }
        __syncthreads();
        if (ty == 0) {
            float s = 0.f;
            #pragma unroll 8
            for (int h = 0; h < 64; ++h) s += b1[h] * W2s[h * 65 + tx];
            bw2s[tx] = s;
        } else if (ty == 1) {
            float s = 0.f;
            #pragma unroll 8
            for (int i = 0; i < 64; ++i) s += Xs[i] * W2s[tx * 65 + i];
            Ps[tx] = s;
        }
        __syncthreads();
        if (tid < F_IN) {
            float s = 0.f;
            #pragma unroll 8
            for (int h = 0; h < 64; ++h) s += Ps[h] * W1s[tid * 65 + h];
            Mout[v * F_IN + tid] = s;
        }
        if (ty == 1) {
            float a = Xs[tx] * bw2s[tx];
            for (int off = 32; off > 0; off >>= 1) a += __shfl_down(a, off);
            if (tx == 0) ABout[v] = a;
        }
        if (ty == 2) {
            float g = Xs[tx] * (v == 0 ? (float)NN * b2[tx] : b2[tx]);
            if (v == 0) g += fw[tx] * cb[tx];
            for (int off = 32; off > 0; off >>= 1) g += __shfl_down(g, off);
            if (tx == 0) G9out[v] = g + (v == 0 ? fb[0] : 0.f);
        }
        return;
    }
    // ---- u-block: recompute M0 (weights only), then u[b][cols] = x[b,col]·M0 ----
    {
        const int ub = blockIdx.x - 521;     // 0..63
        const int b = ub >> 3, ch = ub & 7;  // batch, 512-col chunk
        float* W2s = (float*)sm;
        float* W1s = W2s + 64 * 65;
        float* Xp  = W1s + 40 * 65;
        float* Xs  = Xp + 256;
        float* Ps  = Xs + 64;
        float* M0s = Ps + 64;
        for (int idx = tid; idx < 64 * 64; idx += 256)
            W2s[(idx >> 6) * 65 + (idx & 63)] = W2[idx];
        for (int idx = tid; idx < 40 * 64; idx += 256)
            W1s[(idx >> 6) * 65 + (idx & 63)] = W1[idx];
        {
            float acc = 0.f;
            for (int oo = 0; oo < 16; ++oo) {
                int o = ty * 16 + oo;
                float f = fw[o];
                const float* cp = cw + ((size_t)o * HH + tx) * KW;
                acc += f * (cp[0] + cp[1] + cp[2] + cp[3] + cp[4]);
            }
            Xp[ty * 64 + tx] = acc;
        }
        __syncthreads();
        if (ty == 0) {
            float s = Xp[tx] + Xp[64 + tx] + Xp[128 + tx] + Xp[192 + tx];
            Xs[tx] = s / (float)LL;
        }
        __syncthreads();
        if (ty == 0) {
            float s = 0.f;
            #pragma unroll 8
            for (int i = 0; i < 64; ++i) s += Xs[i] * W2s[tx * 65 + i];
            Ps[tx] = s;
        }
        __syncthreads();
        if (tid < F_IN) {
            float s = 0.f;
            #pragma unroll 8
            for (int h = 0; h < 64; ++h) s += Ps[h] * W1s[tid * 65 + h];
            M0s[tid] = s;
        }
        __syncthreads();
        const float4* M04 = (const float4*)M0s;
        for (int t = tid; t < 512; t += 256) {
            int col = ch * 512 + t;
            const float4* xr = (const float4*)(x + ((size_t)b * NN + col) * F_IN);
            float s = 0.f;
            #pragma unroll
            for (int q = 0; q < F_IN / 4; ++q) {
                float4 a = xr[q], m = M04[q];
                s += a.x * m.x + a.y * m.y + a.z * m.z + a.w * m.w;
            }
            u[(size_t)b * NN + col] = s;
        }
    }
}

// ============ k2: blocks 0..511: stream A (c-weighted) and fold d-term into
//   dataAcc via u; blocks 512..1023: e-contraction folded into dataAcc.
//   Last block (ticket) assembles c0 and writes out. grid 1024, block 256.
__global__ __launch_bounds__(256) void k2(const float4* __restrict__ A4,
                                          const float* __restrict__ part1f,
                                          const float* __restrict__ partEf,
                                          const float* __restrict__ x,
                                          const float* __restrict__ M,
                                          const float* __restrict__ u,
                                          const float* __restrict__ ABp,
                                          const float* __restrict__ G9p,
                                          const float* __restrict__ rpart,
                                          float* __restrict__ dataAcc,
                                          float* __restrict__ sCacc,
                                          int* __restrict__ ticket,
                                          float* __restrict__ out) {
    __shared__ __align__(16) char sm[16384];
    __shared__ float fred[256];
    __shared__ int flag;
    const int tid = threadIdx.x;
    if (blockIdx.x < 512) {
        float* cs = (float*)sm;                           // [128]
        float4 (*redd)[64] = (float4 (*)[64])(sm + 512);  // 4 KB
        float4* t4s = (float4*)(sm + 4608);               // [64] 1 KB
        const int bx = blockIdx.x & 15, by = blockIdx.x >> 4;
        const int tx = tid & 63, ty = tid >> 6;
        const int m0 = by * CHUNK;
        if (tid < CHUNK) {
            float s = 0.f;
            #pragma unroll 8
            for (int y = 0; y < RC; ++y) s += part1f[(size_t)y * NN + m0 + tid];
            cs[tid] = s;
        }
        __syncthreads();
        if (bx == 0 && tid < 64) {
            float t = cs[tid] + cs[tid + 64];
            for (int off = 32; off > 0; off >>= 1) t += __shfl_down(t, off);
            if (tid == 0) atomicAdd(sCacc, t);
        }
        const int c4 = bx * 64 + tx;
        const float4* Ap = A4 + (size_t)(m0 + ty * 32) * COL4 + c4;
        float4 acc = {0.f, 0.f, 0.f, 0.f};
        #pragma unroll 8
        for (int j = 0; j < 32; ++j) f4fma(acc, cs[ty * 32 + j], Ap[(size_t)j * COL4]);
        redd[ty][tx] = acc;
        __syncthreads();
        if (ty == 0) {
            float4 t = redd[0][tx];
            f4add(t, redd[1][tx]);
            f4add(t, redd[2][tx]);
            f4add(t, redd[3][tx]);
            t4s[tx] = t;
        }
        __syncthreads();
        #pragma unroll
        for (int bb = 0; bb < 2; ++bb) {
            int b = ty * 2 + bb;
            float4 t = t4s[tx];
            float4 uu = ((const float4*)(u + (size_t)b * NN))[c4];
            float val = t.x * uu.x + t.y * uu.y + t.z * uu.z + t.w * uu.w;
            for (int off = 32; off > 0; off >>= 1) val += __shfl_down(val, off);
            if (tx == 0) atomicAdd(&dataAcc[b], val);
        }
    } else {
        // ---- e-contraction for v=1..8 ----
        const int idx2 = blockIdx.x - 512;
        const int b = idx2 >> 6, pc = idx2 & 63;
        float* xs  = (float*)sm;              // [64*40]
        float* wls = xs + 64 * F_IN;          // [8*68] padded
        float* Ms  = wls + 8 * 68;            // [320]
        float* red = Ms + 320;                // [256]
        const float4* xsrc4 = (const float4*)(x + ((size_t)b * NN + pc * 64) * F_IN);
        float4* xs4 = (float4*)xs;
        for (int i = tid; i < 64 * F_IN / 4; i += 256) xs4[i] = xsrc4[i];
        for (int i = tid; i < 8 * 16; i += 256) {
            int s = i >> 4, j4 = i & 15;
            float4 t = {0.f, 0.f, 0.f, 0.f};
            #pragma unroll 8
            for (int y = 0; y < RC; ++y)
                f4add(t, ((const float4*)partEf)[((size_t)y * 8 + s) * COL4 + pc * 16 + j4]);
            *(float4*)&wls[s * 68 + j4 * 4] = t;
        }
        for (int i = tid; i < 8 * F_IN; i += 256) Ms[i] = M[F_IN + i];
        __syncthreads();
        float part = 0.f;
        for (int o = tid; o < 8 * F_IN; o += 256) {
            int s = o / F_IN, f = o % F_IN;
            float t = 0.f;
            #pragma unroll 8
            for (int j = 0; j < 64; ++j) t += wls[s * 68 + j] * xs[j * F_IN + f];
            part += Ms[o] * t;
        }
        red[tid] = part;
        __syncthreads();
        for (int off = 128; off > 0; off >>= 1) {
            if (tid < off) red[tid] += red[tid + off];
            __syncthreads();
        }
        if (tid == 0) atomicAdd(&dataAcc[b], red[0]);
    }
    // ---- ticket: last of 1024 blocks finishes ----
    __syncthreads();
    if (tid == 0) {
        __threadfence();
        int old = atomicAdd(ticket, 1);
        flag = (old == 1023) ? 1 : 0;
    }
    __syncthreads();
    if (flag) {
        float val = 0.f;
        if (tid < 128) val += ABp[1 + (tid >> 4)] * rpart[tid];
        if (tid < 9)   val += G9p[tid];
        if (tid == 0)  val += ABp[0] * atomicAdd(sCacc, 0.f);
        fred[tid] = val;
        __syncthreads();
        for (int off = 128; off > 0; off >>= 1) {
            if (tid < off) fred[tid] += fred[tid + off];
            __syncthreads();
        }
        if (tid < BB) out[tid] = fred[0] + atomicAdd(&dataAcc[tid], 0.f);
    }
}

extern "C" void kernel_launch(void* const* d_in, const int* in_sizes, int n_in,
                              void* d_out, int out_size, void* d_ws, size_t ws_size,
                              hipStream_t stream) {
    const float* x  = (const float*)d_in[0];
    const float* A  = (const float*)d_in[1];
    const float* W1 = (const float*)d_in[2];
    const float* b1 = (const float*)d_in[3];
    const float* W2 = (const float*)d_in[4];
    const float* b2 = (const float*)d_in[5];
    const float* cw = (const float*)d_in[6];
    const float* cb = (const float*)d_in[7];
    const float* fw = (const float*)d_in[8];
    const float* fb = (const float*)d_in[9];
    float* out = (float*)d_out;
    float* ws  = (float*)d_ws;

    float* part1 = ws + OFF_P1;
    float* partE = ws + OFF_PE;
    float* u     = ws + OFF_U;
    float* Mmat  = ws + OFF_M;
    float* ABp   = ws + OFF_AB;
    float* G9p   = ws + OFF_G9;
    float* rpart = ws + OFF_RP;
    float* dAcc  = ws + OFF_ACC;
    float* sCa   = ws + OFF_SCA;
    int*   tkt   = (int*)(ws + OFF_TKT);

    const float4* A4 = (const float4*)A;

    k1<<<dim3(585), 256, 0, stream>>>(A4, A, x, (float4*)part1, (float4*)partE, rpart,
                                      W1, b1, W2, b2, cw, cb, fw, fb,
                                      Mmat, ABp, G9p, u, dAcc, sCa, tkt);
    k2<<<dim3(1024), 256, 0, stream>>>(A4, part1, partE, x, Mmat, u,
                                       ABp, G9p, rpart, dAcc, sCa, tkt, out);
}

// Round 11
// 44.170 us; speedup vs baseline: 2.0137x; 2.0137x over previous
//
#include <hip/hip_runtime.h>

#define NN 4096
#define COL4 (NN / 4)      // 1024 float4 per row
#define BB 8
#define F_IN 40
#define HH 64
#define KW 5
#define LL (NN - KW + 1)   // 4092
#define RC 32              // row chunks for A passes (128 rows each)
#define CHUNK (NN / RC)    // 128

// workspace layout (floats)
#define OFF_P1 0                           // [RC][NN]     partial colsums
#define OFF_PE (OFF_P1 + RC * NN)          // [RC][8][NN]  partial e_s
#define OFF_U  (OFF_PE + RC * 8 * NN)      // [BB][NN]     u_b = x[b]·M0
#define OFF_M  (OFF_U + BB * NN)           // [9][F_IN]    adjoint map M
#define OFF_AB (OFF_M + 9 * F_IN)          // [9]          alpha, beta[8]
#define OFF_G9 (OFF_AB + 9)                // [9]          gamma pieces
#define OFF_RP (OFF_G9 + 9)                // [8][16]      rpart
#define OFF_SC (OFF_RP + 128)              // [32]         per-chunk c sums
#define OFF_SD (OFF_SC + 32)               // [8][512]     spartD (d-term per-block dots)
#define OFF_SE (OFF_SD + 8 * 512)          // [8][64]      spartE (e-term dots)

__device__ __forceinline__ int special_row(int s) { return s < 4 ? s : (NN - 8 + s); }
__device__ __forceinline__ void f4add(float4& a, const float4& b) {
    a.x += b.x; a.y += b.y; a.z += b.z; a.w += b.w;
}
__device__ __forceinline__ void f4fma(float4& a, float w, const float4& b) {
    a.x += w * b.x; a.y += w * b.y; a.z += w * b.z; a.w += w * b.w;
}

// ============ k1: bids 0..8 = per-v adjoint (latency-bound, dispatched FIRST);
//   bids 9..72 = u-blocks (u_b = x[b]·M0); bids 73..584 = A streamers
//   (colsum + e_s partials + rpart). grid 585, block 256.
__global__ __launch_bounds__(256) void k1(const float4* __restrict__ A4,
                                          const float* __restrict__ A,
                                          const float* __restrict__ x,
                                          float4* __restrict__ part1,
                                          float4* __restrict__ partE,
                                          float* __restrict__ rpart,
                                          const float* __restrict__ W1,
                                          const float* __restrict__ b1,
                                          const float* __restrict__ W2,
                                          const float* __restrict__ b2,
                                          const float* __restrict__ cw,
                                          const float* __restrict__ cb,
                                          const float* __restrict__ fw,
                                          const float* __restrict__ fb,
                                          float* __restrict__ Mout,
                                          float* __restrict__ ABout,
                                          float* __restrict__ G9out,
                                          float* __restrict__ u) {
    __shared__ __align__(16) char sm[28928];
    const int tid = threadIdx.x;
    const int tx = tid & 63, ty = tid >> 6;
    if (blockIdx.x < 9) {
        // ---- adjoint block for v (weights only, self-contained) ----
        const int v = blockIdx.x;
        float* W2s  = (float*)sm;            // [64*65]
        float* W1s  = W2s + 64 * 65;         // [40*65]
        float* Xp   = W1s + 40 * 65;         // [4][64]
        float* Xs   = Xp + 256;
        float* Ps   = Xs + 64;
        float* bw2s = Ps + 64;
        for (int idx = tid; idx < 64 * 64; idx += 256)
            W2s[(idx >> 6) * 65 + (idx & 63)] = W2[idx];
        for (int idx = tid; idx < 40 * 64; idx += 256)
            W1s[(idx >> 6) * 65 + (idx & 63)] = W1[idx];
        {
            float acc = 0.f;
            for (int oo = 0; oo < 16; ++oo) {
                int o = ty * 16 + oo;
                float f = fw[o];
                const float* cp = cw + ((size_t)o * HH + tx) * KW;
                float w0 = cp[0], w1 = cp[1], w2 = cp[2], w3 = cp[3], w4 = cp[4];
                float coef;
                switch (v) {
                    case 0: coef = w0 + w1 + w2 + w3 + w4; break;
                    case 1: coef = w1 + w2 + w3 + w4; break;
                    case 2: coef = w2 + w3 + w4; break;
                    case 3: coef = w3 + w4; break;
                    case 4: coef = w4; break;
                    case 5: coef = w0; break;
                    case 6: coef = w0 + w1; break;
                    case 7: coef = w0 + w1 + w2; break;
                    default: coef = w0 + w1 + w2 + w3; break;
                }
                acc += f * coef;
            }
            Xp[ty * 64 + tx] = acc;
        }
        __syncthreads();
        if (ty == 0) {
            float s = Xp[tx] + Xp[64 + tx] + Xp[128 + tx] + Xp[192 + tx];
            Xs[tx] = (v == 0 ? 1.f : -1.f) * s / (float)LL;
        }
        __syncthreads();
        if (ty == 0) {
            float s = 0.f;
            #pragma unroll 8
            for (int h = 0; h < 64; ++h) s += b1[h] * W2s[h * 65 + tx];
            bw2s[tx] = s;
        } else if (ty == 1) {
            float s = 0.f;
            #pragma unroll 8
            for (int i = 0; i < 64; ++i) s += Xs[i] * W2s[tx * 65 + i];
            Ps[tx] = s;
        }
        __syncthreads();
        if (tid < F_IN) {
            float s = 0.f;
            #pragma unroll 8
            for (int h = 0; h < 64; ++h) s += Ps[h] * W1s[tid * 65 + h];
            Mout[v * F_IN + tid] = s;
        }
        if (ty == 1) {
            float a = Xs[tx] * bw2s[tx];
            for (int off = 32; off > 0; off >>= 1) a += __shfl_down(a, off);
            if (tx == 0) ABout[v] = a;
        }
        if (ty == 2) {
            float g = Xs[tx] * (v == 0 ? (float)NN * b2[tx] : b2[tx]);
            if (v == 0) g += fw[tx] * cb[tx];
            for (int off = 32; off > 0; off >>= 1) g += __shfl_down(g, off);
            if (tx == 0) G9out[v] = g + (v == 0 ? fb[0] : 0.f);
        }
        return;
    }
    if (blockIdx.x < 73) {
        // ---- u-block: recompute M0 (weights only), then u[b][cols] = x[b,col]·M0 ----
        const int ub = blockIdx.x - 9;       // 0..63
        const int b = ub >> 3, ch = ub & 7;  // batch, 512-col chunk
        float* W2s = (float*)sm;
        float* W1s = W2s + 64 * 65;
        float* Xp  = W1s + 40 * 65;
        float* Xs  = Xp + 256;
        float* Ps  = Xs + 64;
        float* M0s = Ps + 64;
        for (int idx = tid; idx < 64 * 64; idx += 256)
            W2s[(idx >> 6) * 65 + (idx & 63)] = W2[idx];
        for (int idx = tid; idx < 40 * 64; idx += 256)
            W1s[(idx >> 6) * 65 + (idx & 63)] = W1[idx];
        {
            float acc = 0.f;
            for (int oo = 0; oo < 16; ++oo) {
                int o = ty * 16 + oo;
                float f = fw[o];
                const float* cp = cw + ((size_t)o * HH + tx) * KW;
                acc += f * (cp[0] + cp[1] + cp[2] + cp[3] + cp[4]);
            }
            Xp[ty * 64 + tx] = acc;
        }
        __syncthreads();
        if (ty == 0) {
            float s = Xp[tx] + Xp[64 + tx] + Xp[128 + tx] + Xp[192 + tx];
            Xs[tx] = s / (float)LL;
        }
        __syncthreads();
        if (ty == 0) {
            float s = 0.f;
            #pragma unroll 8
            for (int i = 0; i < 64; ++i) s += Xs[i] * W2s[tx * 65 + i];
            Ps[tx] = s;
        }
        __syncthreads();
        if (tid < F_IN) {
            float s = 0.f;
            #pragma unroll 8
            for (int h = 0; h < 64; ++h) s += Ps[h] * W1s[tid * 65 + h];
            M0s[tid] = s;
        }
        __syncthreads();
        const float4* M04 = (const float4*)M0s;
        for (int t = tid; t < 512; t += 256) {
            int col = ch * 512 + t;
            const float4* xr = (const float4*)(x + ((size_t)b * NN + col) * F_IN);
            float s = 0.f;
            #pragma unroll
            for (int q = 0; q < F_IN / 4; ++q) {
                float4 a = xr[q], m = M04[q];
                s += a.x * m.x + a.y * m.y + a.z * m.z + a.w * m.w;
            }
            u[(size_t)b * NN + col] = s;
        }
        return;
    }
    // ---- A streamer ----
    {
        float* wsh = (float*)sm;                                 // [8][128] 4 KB
        float4 (*red3)[3][64] = (float4 (*)[3][64])(sm + 4096);  // 12 KB
        const int sbid = blockIdx.x - 73;
        const int bx = sbid & 15, by = sbid >> 4;
        const int m0 = by * CHUNK;
        for (int idx = tid; idx < 8 * CHUNK; idx += 256) {
            int s = idx >> 7, j = idx & 127;
            wsh[s * CHUNK + j] = A[(size_t)special_row(s) * NN + m0 + j];
        }
        __syncthreads();
        const int c4 = bx * 64 + tx;
        const float4* Ap = A4 + (size_t)(m0 + ty * 32) * COL4 + c4;
        float4 acc[9];
        #pragma unroll
        for (int v = 0; v < 9; ++v) acc[v] = make_float4(0.f, 0.f, 0.f, 0.f);
        #pragma unroll 4
        for (int j = 0; j < 32; ++j) {
            float4 a = Ap[(size_t)j * COL4];
            int jj = ty * 32 + j;
            f4add(acc[0], a);
            #pragma unroll
            for (int s = 0; s < 8; ++s) f4fma(acc[1 + s], wsh[s * CHUNK + jj], a);
        }
        #pragma unroll
        for (int g = 0; g < 3; ++g) {
            #pragma unroll
            for (int vv = 0; vv < 3; ++vv) red3[ty][vv][tx] = acc[g * 3 + vv];
            __syncthreads();
            if (ty == 0) {
                #pragma unroll
                for (int vv = 0; vv < 3; ++vv) {
                    int v = g * 3 + vv;
                    float4 t = red3[0][vv][tx];
                    f4add(t, red3[1][vv][tx]);
                    f4add(t, red3[2][vv][tx]);
                    f4add(t, red3[3][vv][tx]);
                    if (v == 0) part1[(size_t)by * COL4 + c4] = t;
                    else        partE[((size_t)by * 8 + (v - 1)) * COL4 + c4] = t;
                }
            }
            __syncthreads();
        }
        if ((by == 0 || by == 31) && ty == 0) {
            int sbase = (by == 0) ? 0 : 4;
            #pragma unroll
            for (int k = 0; k < 4; ++k) {
                float4 a = A4[(size_t)special_row(sbase + k) * COL4 + c4];
                float v = a.x + a.y + a.z + a.w;
                for (int off = 32; off > 0; off >>= 1) v += __shfl_down(v, off);
                if (tx == 0) rpart[(sbase + k) * 16 + bx] = v;
            }
        }
    }
}

// ============ k2: bids 0..511: e-contraction (independent of part1, FIRST);
//   bids 512..1023: stream A with c-weights, fold directly into spartD[b][block]
//   via u; bx==0 also writes sCpart. grid 1024, block 256.
__global__ __launch_bounds__(256) void k2(const float4* __restrict__ A4,
                                          const float* __restrict__ part1f,
                                          const float* __restrict__ partEf,
                                          const float* __restrict__ x,
                                          const float* __restrict__ M,
                                          const float* __restrict__ u,
                                          float* __restrict__ sCpart,
                                          float* __restrict__ spartD,
                                          float* __restrict__ spartE) {
    __shared__ __align__(16) char sm[16384];
    const int tid = threadIdx.x;
    if (blockIdx.x < 512) {
        // ---- e-contraction for v=1..8 ----
        const int b = blockIdx.x >> 6, pc = blockIdx.x & 63;
        float* xs  = (float*)sm;              // [64*40]
        float* wls = xs + 64 * F_IN;          // [8*68] padded
        float* Ms  = wls + 8 * 68;            // [320]
        float* red = Ms + 320;                // [256]
        const float4* xsrc4 = (const float4*)(x + ((size_t)b * NN + pc * 64) * F_IN);
        float4* xs4 = (float4*)xs;
        for (int i = tid; i < 64 * F_IN / 4; i += 256) xs4[i] = xsrc4[i];
        for (int i = tid; i < 8 * 16; i += 256) {
            int s = i >> 4, j4 = i & 15;
            float4 t = {0.f, 0.f, 0.f, 0.f};
            #pragma unroll 8
            for (int y = 0; y < RC; ++y)
                f4add(t, ((const float4*)partEf)[((size_t)y * 8 + s) * COL4 + pc * 16 + j4]);
            *(float4*)&wls[s * 68 + j4 * 4] = t;
        }
        for (int i = tid; i < 8 * F_IN; i += 256) Ms[i] = M[F_IN + i];
        __syncthreads();
        float part = 0.f;
        for (int o = tid; o < 8 * F_IN; o += 256) {
            int s = o / F_IN, f = o % F_IN;
            float t = 0.f;
            #pragma unroll 8
            for (int j = 0; j < 64; ++j) t += wls[s * 68 + j] * xs[j * F_IN + f];
            part += Ms[o] * t;
        }
        red[tid] = part;
        __syncthreads();
        for (int off = 128; off > 0; off >>= 1) {
            if (tid < off) red[tid] += red[tid + off];
            __syncthreads();
        }
        if (tid == 0) spartE[(size_t)b * 64 + pc] = red[0];
        return;
    }
    // ---- d-streamer ----
    {
        float* cs = (float*)sm;                           // [128]
        float4 (*redd)[64] = (float4 (*)[64])(sm + 512);  // 4 KB
        float4* t4s = (float4*)(sm + 4608);               // [64] 1 KB
        const int sbid = blockIdx.x - 512;
        const int bx = sbid & 15, by = sbid >> 4;
        const int tx = tid & 63, ty = tid >> 6;
        const int m0 = by * CHUNK;
        if (tid < CHUNK) {
            float s = 0.f;
            #pragma unroll 8
            for (int y = 0; y < RC; ++y) s += part1f[(size_t)y * NN + m0 + tid];
            cs[tid] = s;
        }
        __syncthreads();
        if (bx == 0 && tid < 64) {
            float t = cs[tid] + cs[tid + 64];
            for (int off = 32; off > 0; off >>= 1) t += __shfl_down(t, off);
            if (tid == 0) sCpart[by] = t;
        }
        const int c4 = bx * 64 + tx;
        const float4* Ap = A4 + (size_t)(m0 + ty * 32) * COL4 + c4;
        float4 acc = {0.f, 0.f, 0.f, 0.f};
        #pragma unroll 8
        for (int j = 0; j < 32; ++j) f4fma(acc, cs[ty * 32 + j], Ap[(size_t)j * COL4]);
        redd[ty][tx] = acc;
        __syncthreads();
        if (ty == 0) {
            float4 t = redd[0][tx];
            f4add(t, redd[1][tx]);
            f4add(t, redd[2][tx]);
            f4add(t, redd[3][tx]);
            t4s[tx] = t;
        }
        __syncthreads();
        #pragma unroll
        for (int bb = 0; bb < 2; ++bb) {
            int b = ty * 2 + bb;
            float4 t = t4s[tx];
            float4 uu = ((const float4*)(u + (size_t)b * NN))[c4];
            float val = t.x * uu.x + t.y * uu.y + t.z * uu.z + t.w * uu.w;
            for (int off = 32; off > 0; off >>= 1) val += __shfl_down(val, off);
            if (tx == 0) spartD[(size_t)b * 512 + sbid] = val;
        }
    }
}

// ============ k3: tiny finisher, only ~4.7K scalars. grid 1, block 256.
__global__ __launch_bounds__(256) void k3(const float* __restrict__ ABp,
                                          const float* __restrict__ G9p,
                                          const float* __restrict__ rpart,
                                          const float* __restrict__ sCpart,
                                          const float* __restrict__ spartD,
                                          const float* __restrict__ spartE,
                                          float* __restrict__ out) {
    __shared__ float red[256];
    __shared__ float c0s;
    const int tid = threadIdx.x;
    float val = 0.f;
    if (tid < 128) val += ABp[1 + (tid >> 4)] * rpart[tid];
    if (tid < 32)  val += ABp[0] * sCpart[tid];
    if (tid < 9)   val += G9p[tid];
    red[tid] = val;
    __syncthreads();
    for (int off = 128; off > 0; off >>= 1) {
        if (tid < off) red[tid] += red[tid + off];
        __syncthreads();
    }
    if (tid == 0) c0s = red[0];
    __syncthreads();
    const int b = tid >> 5, l = tid & 31;
    float s = 0.f;
    #pragma unroll
    for (int k = l; k < 512; k += 32) s += spartD[(size_t)b * 512 + k];
    s += spartE[(size_t)b * 64 + l] + spartE[(size_t)b * 64 + 32 + l];
    for (int off = 16; off > 0; off >>= 1) s += __shfl_down(s, off, 32);
    if (l == 0) out[b] = c0s + s;
}

extern "C" void kernel_launch(void* const* d_in, const int* in_sizes, int n_in,
                              void* d_out, int out_size, void* d_ws, size_t ws_size,
                              hipStream_t stream) {
    const float* x  = (const float*)d_in[0];
    const float* A  = (const float*)d_in[1];
    const float* W1 = (const float*)d_in[2];
    const float* b1 = (const float*)d_in[3];
    const float* W2 = (const float*)d_in[4];
    const float* b2 = (const float*)d_in[5];
    const float* cw = (const float*)d_in[6];
    const float* cb = (const float*)d_in[7];
    const float* fw = (const float*)d_in[8];
    const float* fb = (const float*)d_in[9];
    float* out = (float*)d_out;
    float* ws  = (float*)d_ws;

    float* part1 = ws + OFF_P1;
    float* partE = ws + OFF_PE;
    float* u     = ws + OFF_U;
    float* Mmat  = ws + OFF_M;
    float* ABp   = ws + OFF_AB;
    float* G9p   = ws + OFF_G9;
    float* rpart = ws + OFF_RP;
    float* sCp   = ws + OFF_SC;
    float* spD   = ws + OFF_SD;
    float* spE   = ws + OFF_SE;

    const float4* A4 = (const float4*)A;

    k1<<<dim3(585), 256, 0, stream>>>(A4, A, x, (float4*)part1, (float4*)partE, rpart,
                                      W1, b1, W2, b2, cw, cb, fw, fb, Mmat, ABp, G9p, u);
    k2<<<dim3(1024), 256, 0, stream>>>(A4, part1, partE, x, Mmat, u, sCp, spD, spE);
    k3<<<dim3(1), 256, 0, stream>>>(ABp, G9p, rpart, sCp, spD, spE, out);
}